// Round 30
// baseline (38.365 us; speedup 1.0000x reference)
//
#include <hip/hip_runtime.h>

#define TL 2048
#define TC 8
#define TK 84
#define TF 4
#define TD 4
#define ROWS 384            // staged LDS rows of 16B: 320 ext + overshoot (6 x 64)
#define PXR 2208            // padded fp16 rows per b: 32 zero + 2048 + 128 zero/pad
#define NFEAT (TD * TK * TF)  // 1344
#define KF (TK * TF)          // 336
#define NQ 8                  // t-chunks per (b,d)

typedef unsigned int u32;
typedef __fp16 hf8 __attribute__((ext_vector_type(8)));
typedef float f32x4 __attribute__((ext_vector_type(4)));

__device__ __forceinline__ u32 pkrtz(float a, float b) {
    return __builtin_bit_cast(u32, __builtin_amdgcn_cvt_pkrtz(a, b));
}
// row swizzle: breaks the 8-row bank period of 16B rows; involution per 64-row group
__device__ __forceinline__ int swzrow(int e) { return e ^ ((e >> 3) & 7); }

// sum over the 16 lanes of each col-group via DPP (VALU only, no LDS)
__device__ __forceinline__ u32 red16(u32 v) {
    v += (u32)__builtin_amdgcn_update_dpp(0, (int)v, 0xB1,  0xF, 0xF, true); // xor1
    v += (u32)__builtin_amdgcn_update_dpp(0, (int)v, 0x4E,  0xF, 0xF, true); // xor2
    v += (u32)__builtin_amdgcn_update_dpp(0, (int)v, 0x141, 0xF, 0xF, true); // xor7 == xor4 here
    v += (u32)__builtin_amdgcn_update_dpp(0, (int)v, 0x140, 0xF, 0xF, true); // xor15 == xor8 here
    return v;
}

// x -> zero-padded fp16 [t][c] rows: xg[b*PXR + t], t = pos + 32
__global__ void mr_prepx(const float* __restrict__ x, uint4* __restrict__ xg) {
    const int idx = blockIdx.x * 256 + threadIdx.x;
    if (idx >= 64 * PXR) return;
    const int b = idx / PXR, pos = (idx % PXR) - 32;
    uint4 v = {0u, 0u, 0u, 0u};
    if (pos >= 0 && pos < TL) {
        const float4* xp = (const float4*)(x + ((size_t)b * TL + pos) * TC);
        const float4 a = xp[0], h = xp[1];
        v.x = pkrtz(a.x, a.y); v.y = pkrtz(a.z, a.w);
        v.z = pkrtz(h.x, h.y); v.w = pkrtz(h.z, h.w);
    }
    xg[idx] = v;
}

// Build masked-weight fragments once: A[d][(kt*3+kb)*64 + lane] fp16x8
__global__ void mr_prepa(const float* __restrict__ kern, const float* __restrict__ cmask,
                         uint4* __restrict__ A) {
    const int idx = blockIdx.x * 256 + threadIdx.x;
    if (idx >= TD * 18 * 64) return;
    const int lane = idx & 63, kbkt = (idx >> 6) % 18, d = idx / (18 * 64);
    const int kt = kbkt / 3, kb = kbkt % 3;
    const int col = lane & 15, lg = lane >> 4;
    const int k = kt * 16 + col, j = kb * 4 + lg;
    uint4 v = {0u, 0u, 0u, 0u};
    if (k < TK && j < 9) {
        const float wv = kern[k * 9 + j];
        const float* mp = cmask + ((size_t)d * TK + k) * TC;
        const float4 m0 = *(const float4*)mp;
        const float4 m1 = *(const float4*)(mp + 4);
        v.x = pkrtz(m0.x != 0.f ? wv : 0.f, m0.y != 0.f ? wv : 0.f);
        v.y = pkrtz(m0.z != 0.f ? wv : 0.f, m0.w != 0.f ? wv : 0.f);
        v.z = pkrtz(m1.x != 0.f ? wv : 0.f, m1.y != 0.f ? wv : 0.f);
        v.w = pkrtz(m1.z != 0.f ? wv : 0.f, m1.w != 0.f ? wv : 0.f);
    }
    A[idx] = v;
}

__global__ __launch_bounds__(256, 4) void mr_main(
    const uint4* __restrict__ xg,    // [64][PXR] fp16 rows (padded)
    const uint4* __restrict__ Ag,    // [D][18*64] fp16x8 fragments
    const float* __restrict__ bias,  // [D, TK, TF]
    int* __restrict__ ws)            // [2048][KF] per-block partial counts
{
    __shared__ __align__(16) uint4 xh[ROWS];     // 6144 B fp16 signal, [t][c] rows
    __shared__ __align__(16) uint4 Alds[1152];   // 18432 B masked-weight fragments
    __shared__ __align__(16) float4 blds[TK];    // 1344 B biases
    __shared__ u32 feats2[6][4][16];             // [kt][wave][lg*4+rg] packed bytes

    const int bx = blockIdx.x;
    const int q = bx & 7, d = (bx >> 3) & 3, b = bx >> 5;
    const int tid = threadIdx.x, lane = tid & 63, w = tid >> 6;
    const int dil = 1 << d, pad = 4 << d;
    const int t0 = q * 256;

    if (tid < TK) blds[tid] = *(const float4*)(bias + ((size_t)d * TK + tid) * TF);

    // ---- bulk-copy precomputed A fragments into LDS (coalesced, no compute) ----
    const uint4* Ad = Ag + d * 1152;
    for (int f = tid; f < 1152; f += 256) Alds[f] = Ad[f];

    // ---- bulk-copy padded fp16 x window into LDS (swizzle on write) ----
    const uint4* xw = xg + (size_t)b * PXR + t0;   // row e = padded row t0+e
    for (int e = tid; e < ROWS; e += 256) xh[swzrow(e)] = xw[e];
    __syncthreads();

    const int col = lane & 15, lg = lane >> 4;

    // ---- hoist ALL kt-invariant B-fragments into registers (12 x hf8) ----
    hf8 bf[12];
    #pragma unroll
    for (int i = 0; i < 4; ++i)
        #pragma unroll
        for (int kb = 0; kb < 3; ++kb) {
            const int e = 32 + col - 4 * dil + (w * 4 + i) * 16 + (kb * 4 + lg) * dil;
            bf[i * 3 + kb] = __builtin_bit_cast(hf8, xh[swzrow(e)]);
        }

    // wave-uniform interior tests per i (t-tile fully inside [pad, TL-pad))
    bool interior[4];
    #pragma unroll
    for (int i = 0; i < 4; ++i) {
        const int tfirst = t0 + (w * 4 + i) * 16;
        interior[i] = (tfirst >= pad) && (tfirst + 16 <= TL - pad);
    }

    // ---- kt loop with af register double-buffer (prefetch kt+1 during kt) ----
    hf8 af0 = __builtin_bit_cast(hf8, Alds[0 * 64 + lane]);
    hf8 af1 = __builtin_bit_cast(hf8, Alds[1 * 64 + lane]);
    hf8 af2 = __builtin_bit_cast(hf8, Alds[2 * 64 + lane]);

    for (int kt = 0; kt < 6; ++kt) {
        hf8 an0, an1, an2;
        if (kt < 5) {
            an0 = __builtin_bit_cast(hf8, Alds[((kt + 1) * 3 + 0) * 64 + lane]);
            an1 = __builtin_bit_cast(hf8, Alds[((kt + 1) * 3 + 1) * 64 + lane]);
            an2 = __builtin_bit_cast(hf8, Alds[((kt + 1) * 3 + 2) * 64 + lane]);
        }

        float4 bq[4];
        #pragma unroll
        for (int rg = 0; rg < 4; ++rg) {
            int k = kt * 16 + lg * 4 + rg;
            k = (k < TK) ? k : (TK - 1);
            bq[rg] = blds[k];
        }

        // packed byte counters: field f at bits [8f,8f+8); per-lane <=4, reduced <=64
        u32 cnt[4] = {0u, 0u, 0u, 0u};

        #pragma unroll
        for (int i = 0; i < 4; ++i) {
            f32x4 C = {0.f, 0.f, 0.f, 0.f};
            C = __builtin_amdgcn_mfma_f32_16x16x32_f16(af0, bf[i * 3 + 0], C, 0, 0, 0);
            C = __builtin_amdgcn_mfma_f32_16x16x32_f16(af1, bf[i * 3 + 1], C, 0, 0, 0);
            C = __builtin_amdgcn_mfma_f32_16x16x32_f16(af2, bf[i * 3 + 2], C, 0, 0, 0);

            if (interior[i]) {
                #pragma unroll
                for (int rg = 0; rg < 4; ++rg) {
                    const float cv = C[rg];
                    cnt[rg] += (cv > bq[rg].x) ? 0x1u : 0u;
                    cnt[rg] += (cv > bq[rg].y) ? 0x100u : 0u;
                    cnt[rg] += (cv > bq[rg].z) ? 0x10000u : 0u;
                    cnt[rg] += (cv > bq[rg].w) ? 0x1000000u : 0u;
                }
            } else {
                const int t = t0 + (w * 4 + i) * 16 + col;
                const bool ok = (t >= pad && t < TL - pad);
                #pragma unroll
                for (int rg = 0; rg < 4; ++rg) {
                    const float cv = C[rg];
                    const bool use = ((d ^ rg) & 1) ? ok : true;  // trim iff (d+k) odd
                    cnt[rg] += (use && cv > bq[rg].x) ? 0x1u : 0u;
                    cnt[rg] += (use && cv > bq[rg].y) ? 0x100u : 0u;
                    cnt[rg] += (use && cv > bq[rg].z) ? 0x10000u : 0u;
                    cnt[rg] += (use && cv > bq[rg].w) ? 0x1000000u : 0u;
                }
            }
        }

        // reduce over the 16 t-columns via DPP (VALU); packed adds can't carry
        #pragma unroll
        for (int rg = 0; rg < 4; ++rg) cnt[rg] = red16(cnt[rg]);

        if (col == 0) {
            #pragma unroll
            for (int rg = 0; rg < 4; ++rg)
                feats2[kt][w][lg * 4 + rg] = cnt[rg];
        }

        if (kt < 5) { af0 = an0; af1 = an1; af2 = an2; }
    }

    // ---- epilogue: unpack per-wave partials, sum over waves, plain stores ----
    __syncthreads();
    for (int idx = tid; idx < KF; idx += 256) {
        const int k = idx >> 2, f = idx & 3;
        const int kt = k >> 4, r = k & 15;      // r = lg*4+rg
        int cnt = 0;
        #pragma unroll
        for (int wv = 0; wv < 4; ++wv)
            cnt += (int)((feats2[kt][wv][r] >> (8 * f)) & 0xFFu);
        ws[(size_t)bx * KF + idx] = cnt;
    }
}

// Reduce 8 q-partials, normalize, write out. Grid covers 64*NFEAT exactly.
__global__ void mr_fin(const int* __restrict__ ws, const float* __restrict__ fmean,
                       const float* __restrict__ fstd, float* __restrict__ out) {
    const int o = blockIdx.x * 256 + threadIdx.x;
    const int fid = o % NFEAT, b = o / NFEAT;
    const int d = fid / KF, idx = fid % KF, k = idx >> 2;
    const int base = ((b * 32 + d * 8) * KF) + idx;
    int cnt = 0;
    #pragma unroll
    for (int q = 0; q < NQ; ++q) cnt += ws[base + q * KF];
    const float denom = ((d + k) & 1) ? (float)(TL - (8 << d)) : (float)TL;
    out[o] = ((float)cnt / denom - fmean[fid]) / fstd[fid];
}

extern "C" void kernel_launch(void* const* d_in, const int* in_sizes, int n_in,
                              void* d_out, int out_size, void* d_ws, size_t ws_size,
                              hipStream_t stream) {
    const float* x     = (const float*)d_in[0];
    const float* kern  = (const float*)d_in[1];
    const float* cmask = (const float*)d_in[2];
    const float* bias  = (const float*)d_in[3];
    const float* fmean = (const float*)d_in[4];
    const float* fstd  = (const float*)d_in[5];
    float* out = (float*)d_out;

    uint4* xgws = (uint4*)d_ws;                              // 64*PXR*16 = 2260992 B
    uint4* Aws  = (uint4*)((char*)d_ws + 64 * PXR * 16);     // 73728 B
    int*   cws  = (int*)((char*)d_ws + 64 * PXR * 16 + TD * 18 * 64 * 16);  // 2752512 B

    hipLaunchKernelGGL(mr_prepx, dim3((64 * PXR + 255) / 256), dim3(256), 0, stream,
                       x, xgws);
    hipLaunchKernelGGL(mr_prepa, dim3((TD * 18 * 64 + 255) / 256), dim3(256), 0, stream,
                       kern, cmask, Aws);
    hipLaunchKernelGGL(mr_main, dim3(64 * TD * NQ), dim3(256), 0, stream,
                       xgws, Aws, bias, cws);
    hipLaunchKernelGGL(mr_fin, dim3(64 * NFEAT / 256), dim3(256), 0, stream,
                       cws, fmean, fstd, out);
}

// Round 31
// 33.406 us; speedup vs baseline: 1.1484x; 1.1484x over previous
//
#include <hip/hip_runtime.h>

#define TL 2048
#define TC 8
#define TK 84
#define TF 4
#define TD 4
#define ROWS 352            // staged LDS rows of 16B: 320 ext + swizzle pad
#define NFEAT (TD * TK * TF)  // 1344
#define KF (TK * TF)          // 336
#define NQ 8                  // t-chunks per (b,d)

typedef unsigned int u32;
typedef __fp16 hf8 __attribute__((ext_vector_type(8)));
typedef float f32x4 __attribute__((ext_vector_type(4)));

__device__ __forceinline__ u32 pkrtz(float a, float b) {
    return __builtin_bit_cast(u32, __builtin_amdgcn_cvt_pkrtz(a, b));
}
// row swizzle: breaks the 8-row bank period of 16B rows; involution per 8-row group
__device__ __forceinline__ int swzrow(int e) { return e ^ ((e >> 3) & 7); }

// sum over the 16 lanes of each col-group via DPP (VALU only, no LDS)
__device__ __forceinline__ u32 red16(u32 v) {
    v += (u32)__builtin_amdgcn_update_dpp(0, (int)v, 0xB1,  0xF, 0xF, true); // xor1
    v += (u32)__builtin_amdgcn_update_dpp(0, (int)v, 0x4E,  0xF, 0xF, true); // xor2
    v += (u32)__builtin_amdgcn_update_dpp(0, (int)v, 0x141, 0xF, 0xF, true); // xor7 == xor4 here
    v += (u32)__builtin_amdgcn_update_dpp(0, (int)v, 0x140, 0xF, 0xF, true); // xor15 == xor8 here
    return v;
}

__global__ __launch_bounds__(256, 4) void mr_main(
    const float* __restrict__ x,     // [B, L, C]
    const float* __restrict__ kern,  // [K, 9]
    const float* __restrict__ cmask, // [D, K, C]
    const float* __restrict__ bias,  // [D, TK, TF]
    int* __restrict__ ws)            // [2048][KF] per-block partial counts
{
    __shared__ __align__(16) uint4 xh[ROWS];     // 5632 B fp16 signal, [t][c] rows
    __shared__ __align__(16) uint4 Alds[1152];   // 18432 B masked-weight fragments
    __shared__ __align__(16) float4 blds[TK];    // 1344 B biases
    __shared__ u32 feats2[6][4][16];             // [kt][wave][lg*4+rg] packed bytes

    const int bx = blockIdx.x;
    const int q = bx & 7, d = (bx >> 3) & 3, b = bx >> 5;
    const int tid = threadIdx.x, lane = tid & 63, w = tid >> 6;
    const int dil = 1 << d, pad = 4 << d;
    const int t0 = q * 256;
    const float* xb = x + (size_t)b * TL * TC;

    if (tid < TK) blds[tid] = *(const float4*)(bias + ((size_t)d * TK + tid) * TF);

    // ---- build A fragments in LDS: Alds[(kt*3+kb)*64 + lg*16 + col] ----
    for (int f = tid; f < 1152; f += 256) {
        const int col = f & 15, lg = (f >> 4) & 3, kbkt = f >> 6;
        const int kt = kbkt / 3, kb = kbkt % 3;
        const int k = kt * 16 + col, j = kb * 4 + lg;
        uint4 v = {0u, 0u, 0u, 0u};
        if (k < TK && j < 9) {
            const float wv = kern[k * 9 + j];
            const float* mp = cmask + ((size_t)d * TK + k) * TC;
            const float4 m0 = *(const float4*)mp;
            const float4 m1 = *(const float4*)(mp + 4);
            v.x = pkrtz(m0.x != 0.f ? wv : 0.f, m0.y != 0.f ? wv : 0.f);
            v.y = pkrtz(m0.z != 0.f ? wv : 0.f, m0.w != 0.f ? wv : 0.f);
            v.z = pkrtz(m1.x != 0.f ? wv : 0.f, m1.y != 0.f ? wv : 0.f);
            v.w = pkrtz(m1.z != 0.f ? wv : 0.f, m1.w != 0.f ? wv : 0.f);
        }
        Alds[f] = v;
    }

    // ---- stage x (fp16, row-swizzled); OOB rows zeroed ----
    for (int e = tid; e < ROWS; e += 256) {
        const int pos = t0 - 32 + e;
        uint4 v = {0u, 0u, 0u, 0u};
        if (pos >= 0 && pos < TL) {
            const float4* xp = (const float4*)(xb + (size_t)pos * TC);
            const float4 a = xp[0], h = xp[1];
            v.x = pkrtz(a.x, a.y); v.y = pkrtz(a.z, a.w);
            v.z = pkrtz(h.x, h.y); v.w = pkrtz(h.z, h.w);
        }
        xh[swzrow(e)] = v;
    }
    __syncthreads();

    const int col = lane & 15, lg = lane >> 4;

    // ---- hoist ALL kt-invariant B-fragments into registers (12 x hf8) ----
    hf8 bf[12];
    #pragma unroll
    for (int i = 0; i < 4; ++i)
        #pragma unroll
        for (int kb = 0; kb < 3; ++kb) {
            const int e = 32 + col - 4 * dil + (w * 4 + i) * 16 + (kb * 4 + lg) * dil;
            bf[i * 3 + kb] = __builtin_bit_cast(hf8, xh[swzrow(e)]);
        }

    // wave-uniform interior tests per i (t-tile fully inside [pad, TL-pad))
    bool interior[4];
    #pragma unroll
    for (int i = 0; i < 4; ++i) {
        const int tfirst = t0 + (w * 4 + i) * 16;
        interior[i] = (tfirst >= pad) && (tfirst + 16 <= TL - pad);
    }

    // ---- kt loop with af register double-buffer (prefetch kt+1 during kt) ----
    hf8 af0 = __builtin_bit_cast(hf8, Alds[0 * 64 + lane]);
    hf8 af1 = __builtin_bit_cast(hf8, Alds[1 * 64 + lane]);
    hf8 af2 = __builtin_bit_cast(hf8, Alds[2 * 64 + lane]);

    for (int kt = 0; kt < 6; ++kt) {
        hf8 an0, an1, an2;
        if (kt < 5) {
            an0 = __builtin_bit_cast(hf8, Alds[((kt + 1) * 3 + 0) * 64 + lane]);
            an1 = __builtin_bit_cast(hf8, Alds[((kt + 1) * 3 + 1) * 64 + lane]);
            an2 = __builtin_bit_cast(hf8, Alds[((kt + 1) * 3 + 2) * 64 + lane]);
        }

        float4 bq[4];
        #pragma unroll
        for (int rg = 0; rg < 4; ++rg) {
            int k = kt * 16 + lg * 4 + rg;
            k = (k < TK) ? k : (TK - 1);
            bq[rg] = blds[k];
        }

        // packed byte counters: field f at bits [8f,8f+8); per-lane <=4, reduced <=64
        u32 cnt[4] = {0u, 0u, 0u, 0u};

        #pragma unroll
        for (int i = 0; i < 4; ++i) {
            f32x4 C = {0.f, 0.f, 0.f, 0.f};
            C = __builtin_amdgcn_mfma_f32_16x16x32_f16(af0, bf[i * 3 + 0], C, 0, 0, 0);
            C = __builtin_amdgcn_mfma_f32_16x16x32_f16(af1, bf[i * 3 + 1], C, 0, 0, 0);
            C = __builtin_amdgcn_mfma_f32_16x16x32_f16(af2, bf[i * 3 + 2], C, 0, 0, 0);

            if (interior[i]) {
                #pragma unroll
                for (int rg = 0; rg < 4; ++rg) {
                    const float cv = C[rg];
                    cnt[rg] += (cv > bq[rg].x) ? 0x1u : 0u;
                    cnt[rg] += (cv > bq[rg].y) ? 0x100u : 0u;
                    cnt[rg] += (cv > bq[rg].z) ? 0x10000u : 0u;
                    cnt[rg] += (cv > bq[rg].w) ? 0x1000000u : 0u;
                }
            } else {
                const int t = t0 + (w * 4 + i) * 16 + col;
                const bool ok = (t >= pad && t < TL - pad);
                #pragma unroll
                for (int rg = 0; rg < 4; ++rg) {
                    const float cv = C[rg];
                    const bool use = ((d ^ rg) & 1) ? ok : true;  // trim iff (d+k) odd
                    cnt[rg] += (use && cv > bq[rg].x) ? 0x1u : 0u;
                    cnt[rg] += (use && cv > bq[rg].y) ? 0x100u : 0u;
                    cnt[rg] += (use && cv > bq[rg].z) ? 0x10000u : 0u;
                    cnt[rg] += (use && cv > bq[rg].w) ? 0x1000000u : 0u;
                }
            }
        }

        // reduce over the 16 t-columns via DPP (VALU); packed adds can't carry
        #pragma unroll
        for (int rg = 0; rg < 4; ++rg) cnt[rg] = red16(cnt[rg]);

        if (col == 0) {
            #pragma unroll
            for (int rg = 0; rg < 4; ++rg)
                feats2[kt][w][lg * 4 + rg] = cnt[rg];
        }

        if (kt < 5) { af0 = an0; af1 = an1; af2 = an2; }
    }

    // ---- epilogue: unpack per-wave partials, sum over waves, plain stores ----
    __syncthreads();
    for (int idx = tid; idx < KF; idx += 256) {
        const int k = idx >> 2, f = idx & 3;
        const int kt = k >> 4, r = k & 15;      // r = lg*4+rg
        int cnt = 0;
        #pragma unroll
        for (int wv = 0; wv < 4; ++wv)
            cnt += (int)((feats2[kt][wv][r] >> (8 * f)) & 0xFFu);
        ws[(size_t)bx * KF + idx] = cnt;
    }
}

// Reduce 8 q-partials, normalize, write out. Grid covers 64*NFEAT exactly.
__global__ void mr_fin(const int* __restrict__ ws, const float* __restrict__ fmean,
                       const float* __restrict__ fstd, float* __restrict__ out) {
    const int o = blockIdx.x * 256 + threadIdx.x;
    const int fid = o % NFEAT, b = o / NFEAT;
    const int d = fid / KF, idx = fid % KF, k = idx >> 2;
    const int base = ((b * 32 + d * 8) * KF) + idx;
    int cnt = 0;
    #pragma unroll
    for (int q = 0; q < NQ; ++q) cnt += ws[base + q * KF];
    const float denom = ((d + k) & 1) ? (float)(TL - (8 << d)) : (float)TL;
    out[o] = ((float)cnt / denom - fmean[fid]) / fstd[fid];
}

extern "C" void kernel_launch(void* const* d_in, const int* in_sizes, int n_in,
                              void* d_out, int out_size, void* d_ws, size_t ws_size,
                              hipStream_t stream) {
    const float* x     = (const float*)d_in[0];
    const float* kern  = (const float*)d_in[1];
    const float* cmask = (const float*)d_in[2];
    const float* bias  = (const float*)d_in[3];
    const float* fmean = (const float*)d_in[4];
    const float* fstd  = (const float*)d_in[5];
    float* out = (float*)d_out;
    int* ws = (int*)d_ws;   // 2048*336*4 = 2752512 B

    hipLaunchKernelGGL(mr_main, dim3(64 * TD * NQ), dim3(256), 0, stream,
                       x, kern, cmask, bias, ws);
    hipLaunchKernelGGL(mr_fin, dim3(64 * NFEAT / 256), dim3(256), 0, stream,
                       ws, fmean, fstd, out);
}